// Round 4
// baseline (204.691 us; speedup 1.0000x reference)
//
#include <hip/hip_runtime.h>

typedef __bf16 bf16x8 __attribute__((ext_vector_type(8)));
typedef float f32x4 __attribute__((ext_vector_type(4)));
typedef float f32x16 __attribute__((ext_vector_type(16)));
typedef unsigned int uint4v __attribute__((ext_vector_type(4)));
typedef unsigned int uint2v __attribute__((ext_vector_type(2)));

#define LOG2E 1.4426950408889634f

static __device__ __forceinline__ unsigned short f2bf(float f) {
  union { float f; unsigned int u; } c; c.f = f;
  return (unsigned short)((c.u + 0x7fffu + ((c.u >> 16) & 1u)) >> 16);
}

static __device__ __forceinline__ void gload16(const void* g, void* l) {
  __builtin_amdgcn_global_load_lds(
      (const __attribute__((address_space(1))) void*)g,
      (__attribute__((address_space(3))) void*)l, 16, 0, 0);
}

// exp2 directly -- LOG2E is pre-folded into Q at the qkv epilogue
static __device__ __forceinline__ float exp2fast(float x) {
#if __has_builtin(__builtin_amdgcn_exp2f)
  return __builtin_amdgcn_exp2f(x);
#else
  return exp2f(x);
#endif
}

static __device__ __forceinline__ f32x16 mfma32(bf16x8 a, bf16x8 b, f32x16 c) {
  return __builtin_amdgcn_mfma_f32_32x32x16_bf16(a, b, c, 0, 0, 0);
}

// pack two f32 -> one u32 of 2 bf16 (low = a, high = b), RNE
static __device__ __forceinline__ unsigned cvt_pk_bf16(float a, float b) {
  unsigned r;
  asm("v_cvt_pk_bf16_f32 %0, %1, %2" : "=v"(r) : "v"(a), "v"(b));
  return r;
}

// swap upper 32 lanes of a with lower 32 lanes of b (lane l <-> l^32 exchange)
static __device__ __forceinline__ void pl32_swap(unsigned& a, unsigned& b) {
#if __has_builtin(__builtin_amdgcn_permlane32_swap)
  uint2v r = __builtin_amdgcn_permlane32_swap(a, b, false, false);
  a = r[0]; b = r[1];
#else
  asm volatile("v_permlane32_swap_b32 %0, %1" : "+v"(a), "+v"(b));
#endif
}

// convert 8 fp32 (two float4) -> swizzled LDS row chunk
static __device__ __forceinline__ void cvt_store8(unsigned short* lds,
                                                  float4 f0, float4 f1) {
  uint4v u = {cvt_pk_bf16(f0.x, f0.y), cvt_pk_bf16(f0.z, f0.w),
              cvt_pk_bf16(f1.x, f1.y), cvt_pk_bf16(f1.z, f1.w)};
  *(uint4v*)lds = u;
}

// ------- QKV projection GEMM, BK=64, swizzled LDS, single-buffered -------
// fp32 inputs converted in staging (reg->cvt_pk->ds_write); no cvt prepass.
// Latency-bound kernel (MfmaUtil 21%, VALU 15%): conversion rides free.
__launch_bounds__(256, 2)
__global__ void qkv_gemm(const float* __restrict__ x,
                         const float* __restrict__ wq,
                         const float* __restrict__ wk,
                         const float* __restrict__ wv,
                         const float* __restrict__ bq,
                         const float* __restrict__ bk,
                         const float* __restrict__ bv,
                         unsigned short* __restrict__ Qo,
                         unsigned short* __restrict__ Ko,
                         unsigned short* __restrict__ VTo) {
  __shared__ unsigned short As[128 * 64];   // 16 KB
  __shared__ unsigned short Bs[128 * 64];   // 16 KB
  const int s0 = blockIdx.x * 128;
  const int n0g = blockIdx.y * 128;
  const int qkv = n0g >> 10;
  const int d0 = n0g & 1023;
  const float* W = (qkv == 0) ? wq : ((qkv == 1) ? wk : wv);
  const float* bias = (qkv == 0) ? bq : ((qkv == 1) ? bk : bv);

  const float* Aptr; const float* Bptr;
  int Aoff, Boff;
  if (qkv < 2) { Aptr = W; Aoff = d0; Bptr = x; Boff = s0; }
  else         { Aptr = x; Aoff = s0; Bptr = W; Boff = d0; }

  const int tid = threadIdx.x;
  const int lane = tid & 63;
  const int wid = tid >> 6;
  const int wm = (wid >> 1) * 64;
  const int wn = (wid & 1) * 64;
  const int lm = lane & 15;
  const int quad = lane >> 4;

  const int srow = tid >> 3, sj = tid & 7;

  f32x4 acc[4][4] = {};

  for (int kk = 0; kk < 1024; kk += 64) {
#pragma unroll
    for (int t = 0; t < 4; ++t) {
      const int row = srow + t * 32;
      const float4* ga =
          (const float4*)(Aptr + (size_t)(Aoff + row) * 1024 + kk + sj * 8);
      const float4* gb =
          (const float4*)(Bptr + (size_t)(Boff + row) * 1024 + kk + sj * 8);
      float4 a0 = ga[0], a1 = ga[1];
      float4 b0 = gb[0], b1 = gb[1];
      const int off = row * 64 + ((sj ^ (row & 7)) << 3);
      cvt_store8(&As[off], a0, a1);
      cvt_store8(&Bs[off], b0, b1);
    }
    __syncthreads();
#pragma unroll
    for (int h = 0; h < 2; ++h) {
      bf16x8 af[4], bff[4];
#pragma unroll
      for (int mt = 0; mt < 4; ++mt) {
        int r = wm + mt * 16 + lm;
        af[mt] = *(const bf16x8*)(&As[r * 64 + (((h * 4 + quad) ^ (r & 7)) * 8)]);
      }
#pragma unroll
      for (int nt = 0; nt < 4; ++nt) {
        int r = wn + nt * 16 + lm;
        bff[nt] = *(const bf16x8*)(&Bs[r * 64 + (((h * 4 + quad) ^ (r & 7)) * 8)]);
      }
#pragma unroll
      for (int mt = 0; mt < 4; ++mt)
#pragma unroll
        for (int nt = 0; nt < 4; ++nt)
          acc[mt][nt] = __builtin_amdgcn_mfma_f32_16x16x32_bf16(
              af[mt], bff[nt], acc[mt][nt], 0, 0, 0);
    }
    __syncthreads();
  }

  if (qkv < 2) {
    unsigned short* OUT = (qkv == 0) ? Qo : Ko;
    // Q pre-scale carries SCALE * LOG2E so attention can use exp2 directly
    const float scale = (qkv == 0) ? (0.125f * LOG2E) : 1.0f;
#pragma unroll
    for (int mt = 0; mt < 4; ++mt) {
      const int d = d0 + wm + mt * 16 + quad * 4;
      const int g = d >> 8, hpg = (d >> 6) & 3, hd = d & 63;
      const float4 bb = *(const float4*)(bias + d);
#pragma unroll
      for (int nt = 0; nt < 4; ++nt) {
        const int srow2 = s0 + wn + nt * 16 + lm;
        const int bidx = srow2 >> 11, s = srow2 & 2047;
        const int head = (bidx * 4 + g) * 4 + hpg;
        ushort4 o;
        o.x = f2bf((acc[mt][nt][0] + bb.x) * scale);
        o.y = f2bf((acc[mt][nt][1] + bb.y) * scale);
        o.z = f2bf((acc[mt][nt][2] + bb.z) * scale);
        o.w = f2bf((acc[mt][nt][3] + bb.w) * scale);
        *(ushort4*)(OUT + (size_t)head * 131072 + (size_t)s * 64 + hd) = o;
      }
    }
  } else {
#pragma unroll
    for (int nt = 0; nt < 4; ++nt) {
      const int d = d0 + wn + nt * 16 + lm;
      const int g = d >> 8, hpg = (d >> 6) & 3, hd = d & 63;
      const float bb = bias[d];
#pragma unroll
      for (int mt = 0; mt < 4; ++mt) {
        const int sbase = s0 + wm + mt * 16 + quad * 4;
        const int bidx = sbase >> 11, s = sbase & 2047;
        const int head = (bidx * 4 + g) * 4 + hpg;
        ushort4 o;
        o.x = f2bf(acc[mt][nt][0] + bb);
        o.y = f2bf(acc[mt][nt][1] + bb);
        o.z = f2bf(acc[mt][nt][2] + bb);
        o.w = f2bf(acc[mt][nt][3] + bb);
        *(ushort4*)(VTo + (size_t)head * 131072 + (size_t)hd * 2048 + s) = o;
      }
    }
  }
}

// ---- K/V staging (128-kv tiles), 16B-chunk XOR swizzle, linear LDS dest ----
static __device__ __forceinline__ void stage_kv(
    const unsigned short* Kh, const unsigned short* Vh, int kv0,
    unsigned short* ksl, unsigned short* vsl, int tid) {
#pragma unroll
  for (int t = 0; t < 4; ++t) {
    int i = t * 256 + tid;
    int r = i >> 3, j = i & 7;
    gload16(Kh + (size_t)(kv0 + r) * 64 + ((j ^ (r & 7)) << 3),
            ksl + (size_t)i * 8);
  }
#pragma unroll
  for (int t = 0; t < 4; ++t) {
    int i = t * 256 + tid;
    int r = i >> 4, j = i & 15;
    gload16(Vh + (size_t)r * 2048 + kv0 + ((j ^ (r & 15)) << 3),
            vsl + (size_t)i * 8);
  }
}

// ------ attention v5: 32x32x16 MFMA for QK and PV, in-register P via
// cvt_pk_bf16 + permlane32_swap (T12).  q128/kv128 tile, waves 2x2 over
// (kv x q).  Confirmed <=44 us (dropped out of top-5 since R2).
__launch_bounds__(256, 2)
__global__ void attn_kernel(const unsigned short* __restrict__ Q,
                            const unsigned short* __restrict__ K,
                            const unsigned short* __restrict__ VT,
                            unsigned short* __restrict__ ctx) {
  __shared__ __align__(16) unsigned char smem[65536];

  const int f = blockIdx.x;
  const int xcd = f & 7;
  const int idx = f >> 3;
  const int head = xcd * 4 + (idx & 3);   // heads clustered per XCD
  const int q0 = (idx >> 2) * 128;
  const int b = head >> 4;
  const int colbase = (head & 15) * 64;

  const unsigned short* Qh = Q + (size_t)head * 131072;
  const unsigned short* Kh = K + (size_t)head * 131072;
  const unsigned short* Vh = VT + (size_t)head * 131072;

  const int tid = threadIdx.x;
  const int lane = tid & 63;
  const int w = tid >> 6;
  const int wq = w & 1;
  const int wkv = w >> 1;
  const int l31 = lane & 31;
  const int hi = lane >> 5;

  stage_kv(Kh, Vh, 0, (unsigned short*)smem,
           (unsigned short*)(smem + 32768), tid);

  // Q B-fragments: B[k=d][col=q]: lane holds Q[q0+...+l31][s*16 + hi*8 + j]
  bf16x8 qf[2][4];
#pragma unroll
  for (int qs = 0; qs < 2; ++qs) {
    const size_t qrow = (size_t)(q0 + wq * 64 + qs * 32 + l31);
#pragma unroll
    for (int s = 0; s < 4; ++s)
      qf[qs][s] = *(const bf16x8*)(Qh + qrow * 64 + s * 16 + hi * 8);
  }

  // it-invariant LDS read offsets (elements)
  int koff[2][4];
#pragma unroll
  for (int kb = 0; kb < 2; ++kb) {
    const int row = wkv * 64 + kb * 32 + l31;
#pragma unroll
    for (int s = 0; s < 4; ++s) {
      const int c = s * 2 + hi;
      koff[kb][s] = row * 64 + ((c ^ (row & 7)) << 3);
    }
  }
  int voff[2][2][2];
#pragma unroll
  for (int kb = 0; kb < 2; ++kb)
#pragma unroll
    for (int db = 0; db < 2; ++db) {
      const int row = db * 32 + l31;
#pragma unroll
      for (int t = 0; t < 2; ++t) {
        const int c = wkv * 8 + kb * 4 + t * 2 + hi;
        voff[kb][db][t] = row * 128 + ((c ^ (row & 15)) << 3);
      }
    }

  __syncthreads();

  float psum[2] = {0.f, 0.f};
  f32x16 oacc[2][2] = {};   // [qsub][db]: D[d][q], d = db*32 + crow(reg,hi)

  for (int it = 0; it < 16; ++it) {
    const int buf = it & 1;
    const unsigned short* kbuf = (const unsigned short*)(smem + buf * 16384);
    const unsigned short* vbuf =
        (const unsigned short*)(smem + 32768 + buf * 16384);
    if (it < 15)
      stage_kv(Kh, Vh, (it + 1) * 128,
               (unsigned short*)(smem + (buf ^ 1) * 16384),
               (unsigned short*)(smem + 32768 + (buf ^ 1) * 16384), tid);

#pragma unroll
    for (int kb = 0; kb < 2; ++kb) {
      bf16x8 kf[4], vf[2][2];
#pragma unroll
      for (int s = 0; s < 4; ++s)
        kf[s] = *(const bf16x8*)(kbuf + koff[kb][s]);
#pragma unroll
      for (int db = 0; db < 2; ++db)
#pragma unroll
        for (int t = 0; t < 2; ++t)
          vf[db][t] = *(const bf16x8*)(vbuf + voff[kb][db][t]);

#pragma unroll
      for (int qs = 0; qs < 2; ++qs) {
        f32x16 sc = {};
#pragma unroll
        for (int s = 0; s < 4; ++s)
          sc = mfma32(kf[s], qf[qs][s], sc);

        float e[16];
#pragma unroll
        for (int r = 0; r < 16; ++r) e[r] = exp2fast(sc[r]);
        {
          float t0 = (e[0] + e[1]) + (e[2] + e[3]);
          float t1 = (e[4] + e[5]) + (e[6] + e[7]);
          float t2 = (e[8] + e[9]) + (e[10] + e[11]);
          float t3 = (e[12] + e[13]) + (e[14] + e[15]);
          psum[qs] += (t0 + t1) + (t2 + t3);
        }
        unsigned p[8];
#pragma unroll
        for (int j = 0; j < 8; ++j) p[j] = cvt_pk_bf16(e[2 * j], e[2 * j + 1]);
        // redistribute into 32x32x16 B-fragment layout (2 swaps per 16-kv)
        pl32_swap(p[0], p[2]); pl32_swap(p[1], p[3]);   // kv [0,16)
        pl32_swap(p[4], p[6]); pl32_swap(p[5], p[7]);   // kv [16,32)
        uint4v u0 = {p[0], p[1], p[2], p[3]};
        uint4v u1 = {p[4], p[5], p[6], p[7]};
        const bf16x8 B0 = __builtin_bit_cast(bf16x8, u0);
        const bf16x8 B1 = __builtin_bit_cast(bf16x8, u1);
#pragma unroll
        for (int db = 0; db < 2; ++db) {
          oacc[qs][db] = mfma32(vf[db][0], B0, oacc[qs][db]);
          oacc[qs][db] = mfma32(vf[db][1], B1, oacc[qs][db]);
        }
      }
    }
    __syncthreads();
  }

  // combine the two hi-halves of each q-row's partial sum
#pragma unroll
  for (int qs = 0; qs < 2; ++qs)
    psum[qs] += __shfl_xor(psum[qs], 32, 64);

  float* red = (float*)smem;               // 128 x 68 floats = 34816 B
  float* psred = (float*)(smem + 34816);   // 128 floats
  if (wkv == 1) {
#pragma unroll
    for (int qs = 0; qs < 2; ++qs) {
      const int qi = wq * 64 + qs * 32 + l31;
      if (hi == 0) psred[qi] = psum[qs];
#pragma unroll
      for (int db = 0; db < 2; ++db)
#pragma unroll
        for (int g = 0; g < 4; ++g) {
          f32x4 ov;
          ov[0] = oacc[qs][db][4 * g + 0];
          ov[1] = oacc[qs][db][4 * g + 1];
          ov[2] = oacc[qs][db][4 * g + 2];
          ov[3] = oacc[qs][db][4 * g + 3];
          *(f32x4*)(red + qi * 68 + db * 32 + g * 8 + hi * 4) = ov;
        }
    }
  }
  __syncthreads();
  if (wkv == 0) {
#pragma unroll
    for (int qs = 0; qs < 2; ++qs) {
      const int qi = wq * 64 + qs * 32 + l31;
      const float inv = 1.0f / (psum[qs] + psred[qi]);
      const size_t row = (size_t)(b * 2048 + q0 + qi);
#pragma unroll
      for (int db = 0; db < 2; ++db)
#pragma unroll
        for (int g = 0; g < 4; ++g) {
          f32x4 o = *(const f32x4*)(red + qi * 68 + db * 32 + g * 8 + hi * 4);
          ushort4 st;
          st.x = f2bf((o[0] + oacc[qs][db][4 * g + 0]) * inv);
          st.y = f2bf((o[1] + oacc[qs][db][4 * g + 1]) * inv);
          st.z = f2bf((o[2] + oacc[qs][db][4 * g + 2]) * inv);
          st.w = f2bf((o[3] + oacc[qs][db][4 * g + 3]) * inv);
          *(ushort4*)(ctx + row * 1024 + colbase + db * 32 + g * 8 + hi * 4) =
              st;
        }
    }
  }
}

// -- output projection: o128 x s64 tile, BK=64, swizzled LDS, single-buffer --
// Wo fp32 converted in staging; ctx stays bf16 via global_load_lds.
__launch_bounds__(256, 4)
__global__ void out_gemm(const unsigned short* __restrict__ A,   // ctx [4096][1024]
                         const float* __restrict__ Wo,           // fp32 [1024][1024]
                         const float* __restrict__ bo,
                         float* __restrict__ out) {
  __shared__ unsigned short As[128 * 64];   // Wo rows (o)   16 KB
  __shared__ unsigned short Bs[64 * 64];    // ctx rows (s)   8 KB
  const int s0 = blockIdx.x * 64;
  const int o0 = blockIdx.y * 128;

  const int tid = threadIdx.x;
  const int lane = tid & 63;
  const int wid = tid >> 6;
  const int wm = (wid >> 1) * 64;   // o
  const int wn = (wid & 1) * 32;    // s
  const int lm = lane & 15;
  const int quad = lane >> 4;
  const int srow = tid >> 3, sj = tid & 7;

  f32x4 acc[4][2] = {};

  for (int kk = 0; kk < 1024; kk += 64) {
    // ctx (bf16): async DMA first so it overlaps the Wo convert
#pragma unroll
    for (int t = 0; t < 2; ++t) {
      int i = t * 256 + tid;
      int row = i >> 3, tp = i & 7;
      int seg = tp ^ (row & 7);
      gload16(A + (size_t)(s0 + row) * 1024 + kk + seg * 8, Bs + (size_t)i * 8);
    }
    // Wo (fp32): reg-stage + convert + swizzled ds_write
#pragma unroll
    for (int t = 0; t < 4; ++t) {
      const int row = srow + t * 32;
      const float4* g =
          (const float4*)(Wo + (size_t)(o0 + row) * 1024 + kk + sj * 8);
      float4 f0 = g[0], f1 = g[1];
      cvt_store8(&As[row * 64 + ((sj ^ (row & 7)) << 3)], f0, f1);
    }
    __syncthreads();
#pragma unroll
    for (int h = 0; h < 2; ++h) {
      bf16x8 af[4], bff[2];
#pragma unroll
      for (int mt = 0; mt < 4; ++mt) {
        int r = wm + mt * 16 + lm;
        af[mt] = *(const bf16x8*)(&As[r * 64 + (((h * 4 + quad) ^ (r & 7)) * 8)]);
      }
#pragma unroll
      for (int nt = 0; nt < 2; ++nt) {
        int r = wn + nt * 16 + lm;
        bff[nt] = *(const bf16x8*)(&Bs[r * 64 + (((h * 4 + quad) ^ (r & 7)) * 8)]);
      }
#pragma unroll
      for (int mt = 0; mt < 4; ++mt)
#pragma unroll
        for (int nt = 0; nt < 2; ++nt)
          acc[mt][nt] = __builtin_amdgcn_mfma_f32_16x16x32_bf16(
              af[mt], bff[nt], acc[mt][nt], 0, 0, 0);
    }
    __syncthreads();
  }

#pragma unroll
  for (int mt = 0; mt < 4; ++mt) {
    const int o = o0 + wm + mt * 16 + quad * 4;
    const float4 bb = *(const float4*)(bo + o);
#pragma unroll
    for (int nt = 0; nt < 2; ++nt) {
      const int s = s0 + wn + nt * 16 + lm;
      float4 v;
      v.x = acc[mt][nt][0] + bb.x;
      v.y = acc[mt][nt][1] + bb.y;
      v.z = acc[mt][nt][2] + bb.z;
      v.w = acc[mt][nt][3] + bb.w;
      *(float4*)(out + (size_t)s * 1024 + o) = v;
    }
  }
}

extern "C" void kernel_launch(void* const* d_in, const int* in_sizes, int n_in,
                              void* d_out, int out_size, void* d_ws, size_t ws_size,
                              hipStream_t stream) {
  const float* x  = (const float*)d_in[0];
  const float* Wq = (const float*)d_in[1];
  const float* bq = (const float*)d_in[2];
  const float* Wk = (const float*)d_in[3];
  const float* bk = (const float*)d_in[4];
  const float* Wv = (const float*)d_in[5];
  const float* bv = (const float*)d_in[6];
  const float* Wo = (const float*)d_in[7];
  const float* bo = (const float*)d_in[8];
  float* out = (float*)d_out;

  char* ws = (char*)d_ws;
  unsigned short* Qb  = (unsigned short*)(ws + 0);          //  8 MB [32][2048][64]
  unsigned short* Kb  = (unsigned short*)(ws + 8388608);    //  8 MB [32][2048][64]
  unsigned short* VTb = (unsigned short*)(ws + 16777216);   //  8 MB [32][64][2048]
  unsigned short* ctxb= (unsigned short*)(ws + 25165824);   //  8 MB [4096][1024]
  if (ws_size < 33554432) return;

  qkv_gemm<<<dim3(32, 24), 256, 0, stream>>>(x, Wq, Wk, Wv, bq, bk, bv,
                                             Qb, Kb, VTb);
  attn_kernel<<<dim3(512), 256, 0, stream>>>(Qb, Kb, VTb, ctxb);
  out_gemm<<<dim3(64, 8), 256, 0, stream>>>(ctxb, Wo, bo, out);
}

// Round 5
// 175.561 us; speedup vs baseline: 1.1659x; 1.1659x over previous
//
#include <hip/hip_runtime.h>

typedef __bf16 bf16x8 __attribute__((ext_vector_type(8)));
typedef float f32x4 __attribute__((ext_vector_type(4)));
typedef float f32x16 __attribute__((ext_vector_type(16)));
typedef unsigned int uint4v __attribute__((ext_vector_type(4)));
typedef unsigned int uint2v __attribute__((ext_vector_type(2)));

#define LOG2E 1.4426950408889634f

static __device__ __forceinline__ unsigned short f2bf(float f) {
  union { float f; unsigned int u; } c; c.f = f;
  return (unsigned short)((c.u + 0x7fffu + ((c.u >> 16) & 1u)) >> 16);
}

static __device__ __forceinline__ void gload16(const void* g, void* l) {
  __builtin_amdgcn_global_load_lds(
      (const __attribute__((address_space(1))) void*)g,
      (__attribute__((address_space(3))) void*)l, 16, 0, 0);
}

// exp2 directly -- LOG2E is pre-folded into Q at the qkv epilogue
static __device__ __forceinline__ float exp2fast(float x) {
#if __has_builtin(__builtin_amdgcn_exp2f)
  return __builtin_amdgcn_exp2f(x);
#else
  return exp2f(x);
#endif
}

static __device__ __forceinline__ f32x16 mfma32(bf16x8 a, bf16x8 b, f32x16 c) {
  return __builtin_amdgcn_mfma_f32_32x32x16_bf16(a, b, c, 0, 0, 0);
}

// pack two f32 -> one u32 of 2 bf16 (low = a, high = b), RNE
static __device__ __forceinline__ unsigned cvt_pk_bf16(float a, float b) {
  unsigned r;
  asm("v_cvt_pk_bf16_f32 %0, %1, %2" : "=v"(r) : "v"(a), "v"(b));
  return r;
}

// swap upper 32 lanes of a with lower 32 lanes of b (lane l <-> l^32 exchange)
static __device__ __forceinline__ void pl32_swap(unsigned& a, unsigned& b) {
#if __has_builtin(__builtin_amdgcn_permlane32_swap)
  uint2v r = __builtin_amdgcn_permlane32_swap(a, b, false, false);
  a = r[0]; b = r[1];
#else
  asm volatile("v_permlane32_swap_b32 %0, %1" : "+v"(a), "+v"(b));
#endif
}

// ---------------- fused fp32 -> bf16 convert for x + 4 weights ----------------
__global__ void cvt_all(const float* __restrict__ x,
                        const float* __restrict__ Wq,
                        const float* __restrict__ Wk,
                        const float* __restrict__ Wv,
                        const float* __restrict__ Wo,
                        ushort4* __restrict__ dst) {
  int i = blockIdx.x * 256 + threadIdx.x;
  const float* src;
  int off;
  if (i < 1048576) {
    src = x; off = i;
  } else {
    int t = (i - 1048576) >> 18;
    off = (i - 1048576) & 262143;
    src = (t == 0) ? Wq : (t == 1) ? Wk : (t == 2) ? Wv : Wo;
  }
  float4 f = ((const float4*)src)[off];
  ushort4 o;
  o.x = f2bf(f.x); o.y = f2bf(f.y); o.z = f2bf(f.z); o.w = f2bf(f.w);
  dst[i] = o;
}

// ---------------- QKV projection GEMM, BK=64, swizzled LDS ----------------
// Single-buffered (dbuf measured null->regressive, R3).  launch_bounds 4/EU:
// VGPR 88 <= 128 and LDS 32 KB permit 4 blocks/CU; cross-block overlap is the
// mechanism that hides the per-K-step barrier drain (m114).
__launch_bounds__(256, 4)
__global__ void qkv_gemm(const unsigned short* __restrict__ xb,
                         const unsigned short* __restrict__ wq,
                         const unsigned short* __restrict__ wk,
                         const unsigned short* __restrict__ wv,
                         const float* __restrict__ bq,
                         const float* __restrict__ bk,
                         const float* __restrict__ bv,
                         unsigned short* __restrict__ Qo,
                         unsigned short* __restrict__ Ko,
                         unsigned short* __restrict__ VTo) {
  __shared__ unsigned short As[128 * 64];   // 16 KB
  __shared__ unsigned short Bs[128 * 64];   // 16 KB
  const int s0 = blockIdx.x * 128;
  const int n0g = blockIdx.y * 128;
  const int qkv = n0g >> 10;
  const int d0 = n0g & 1023;
  const unsigned short* W = (qkv == 0) ? wq : ((qkv == 1) ? wk : wv);
  const float* bias = (qkv == 0) ? bq : ((qkv == 1) ? bk : bv);

  const unsigned short* Aptr; const unsigned short* Bptr;
  int Aoff, Boff;
  if (qkv < 2) { Aptr = W;  Aoff = d0; Bptr = xb; Boff = s0; }
  else         { Aptr = xb; Aoff = s0; Bptr = W;  Boff = d0; }

  const int tid = threadIdx.x;
  const int lane = tid & 63;
  const int wid = tid >> 6;
  const int wm = (wid >> 1) * 64;
  const int wn = (wid & 1) * 64;
  const int lm = lane & 15;
  const int quad = lane >> 4;

  f32x4 acc[4][4] = {};

  for (int kk = 0; kk < 1024; kk += 64) {
#pragma unroll
    for (int t = 0; t < 4; ++t) {
      int i = t * 256 + tid;
      int row = i >> 3, tp = i & 7;
      int seg = tp ^ (row & 7);
      gload16(Aptr + (size_t)(Aoff + row) * 1024 + kk + seg * 8,
              As + (size_t)i * 8);
      gload16(Bptr + (size_t)(Boff + row) * 1024 + kk + seg * 8,
              Bs + (size_t)i * 8);
    }
    __syncthreads();
#pragma unroll
    for (int h = 0; h < 2; ++h) {
      bf16x8 af[4], bff[4];
#pragma unroll
      for (int mt = 0; mt < 4; ++mt) {
        int r = wm + mt * 16 + lm;
        af[mt] = *(const bf16x8*)(As + r * 64 + (((h * 4 + quad) ^ (r & 7)) * 8));
      }
#pragma unroll
      for (int nt = 0; nt < 4; ++nt) {
        int r = wn + nt * 16 + lm;
        bff[nt] = *(const bf16x8*)(Bs + r * 64 + (((h * 4 + quad) ^ (r & 7)) * 8));
      }
#pragma unroll
      for (int mt = 0; mt < 4; ++mt)
#pragma unroll
        for (int nt = 0; nt < 4; ++nt)
          acc[mt][nt] = __builtin_amdgcn_mfma_f32_16x16x32_bf16(
              af[mt], bff[nt], acc[mt][nt], 0, 0, 0);
    }
    __syncthreads();
  }

  if (qkv < 2) {
    unsigned short* OUT = (qkv == 0) ? Qo : Ko;
    // Q pre-scale carries SCALE * LOG2E so attention can use exp2 directly
    const float scale = (qkv == 0) ? (0.125f * LOG2E) : 1.0f;
#pragma unroll
    for (int mt = 0; mt < 4; ++mt) {
      const int d = d0 + wm + mt * 16 + quad * 4;
      const int g = d >> 8, hpg = (d >> 6) & 3, hd = d & 63;
      const float4 bb = *(const float4*)(bias + d);
#pragma unroll
      for (int nt = 0; nt < 4; ++nt) {
        const int srow = s0 + wn + nt * 16 + lm;
        const int bidx = srow >> 11, s = srow & 2047;
        const int head = (bidx * 4 + g) * 4 + hpg;
        ushort4 o;
        o.x = f2bf((acc[mt][nt][0] + bb.x) * scale);
        o.y = f2bf((acc[mt][nt][1] + bb.y) * scale);
        o.z = f2bf((acc[mt][nt][2] + bb.z) * scale);
        o.w = f2bf((acc[mt][nt][3] + bb.w) * scale);
        *(ushort4*)(OUT + (size_t)head * 131072 + (size_t)s * 64 + hd) = o;
      }
    }
  } else {
#pragma unroll
    for (int nt = 0; nt < 4; ++nt) {
      const int d = d0 + wn + nt * 16 + lm;
      const int g = d >> 8, hpg = (d >> 6) & 3, hd = d & 63;
      const float bb = bias[d];
#pragma unroll
      for (int mt = 0; mt < 4; ++mt) {
        const int sbase = s0 + wm + mt * 16 + quad * 4;
        const int bidx = sbase >> 11, s = sbase & 2047;
        const int head = (bidx * 4 + g) * 4 + hpg;
        ushort4 o;
        o.x = f2bf(acc[mt][nt][0] + bb);
        o.y = f2bf(acc[mt][nt][1] + bb);
        o.z = f2bf(acc[mt][nt][2] + bb);
        o.w = f2bf(acc[mt][nt][3] + bb);
        *(ushort4*)(VTo + (size_t)head * 131072 + (size_t)hd * 2048 + s) = o;
      }
    }
  }
}

// ---- K/V staging (128-kv tiles), 16B-chunk XOR swizzle, linear LDS dest ----
static __device__ __forceinline__ void stage_kv(
    const unsigned short* Kh, const unsigned short* Vh, int kv0,
    unsigned short* ksl, unsigned short* vsl, int tid) {
#pragma unroll
  for (int t = 0; t < 4; ++t) {
    int i = t * 256 + tid;
    int r = i >> 3, j = i & 7;
    gload16(Kh + (size_t)(kv0 + r) * 64 + ((j ^ (r & 7)) << 3),
            ksl + (size_t)i * 8);
  }
#pragma unroll
  for (int t = 0; t < 4; ++t) {
    int i = t * 256 + tid;
    int r = i >> 4, j = i & 15;
    gload16(Vh + (size_t)r * 2048 + kv0 + ((j ^ (r & 15)) << 3),
            vsl + (size_t)i * 8);
  }
}

// ------ attention v5: 32x32x16 MFMA for QK and PV, in-register P via
// cvt_pk_bf16 + permlane32_swap (T12).  q128/kv128 tile, waves 2x2 over
// (kv x q).  Confirmed <=44 us (dropped out of top-5 since R2).
__launch_bounds__(256, 2)
__global__ void attn_kernel(const unsigned short* __restrict__ Q,
                            const unsigned short* __restrict__ K,
                            const unsigned short* __restrict__ VT,
                            unsigned short* __restrict__ ctx) {
  __shared__ __align__(16) unsigned char smem[65536];

  const int f = blockIdx.x;
  const int xcd = f & 7;
  const int idx = f >> 3;
  const int head = xcd * 4 + (idx & 3);   // heads clustered per XCD
  const int q0 = (idx >> 2) * 128;
  const int b = head >> 4;
  const int colbase = (head & 15) * 64;

  const unsigned short* Qh = Q + (size_t)head * 131072;
  const unsigned short* Kh = K + (size_t)head * 131072;
  const unsigned short* Vh = VT + (size_t)head * 131072;

  const int tid = threadIdx.x;
  const int lane = tid & 63;
  const int w = tid >> 6;
  const int wq = w & 1;
  const int wkv = w >> 1;
  const int l31 = lane & 31;
  const int hi = lane >> 5;

  stage_kv(Kh, Vh, 0, (unsigned short*)smem,
           (unsigned short*)(smem + 32768), tid);

  // Q B-fragments: B[k=d][col=q]: lane holds Q[q0+...+l31][s*16 + hi*8 + j]
  bf16x8 qf[2][4];
#pragma unroll
  for (int qs = 0; qs < 2; ++qs) {
    const size_t qrow = (size_t)(q0 + wq * 64 + qs * 32 + l31);
#pragma unroll
    for (int s = 0; s < 4; ++s)
      qf[qs][s] = *(const bf16x8*)(Qh + qrow * 64 + s * 16 + hi * 8);
  }

  // it-invariant LDS read offsets (elements)
  int koff[2][4];
#pragma unroll
  for (int kb = 0; kb < 2; ++kb) {
    const int row = wkv * 64 + kb * 32 + l31;
#pragma unroll
    for (int s = 0; s < 4; ++s) {
      const int c = s * 2 + hi;
      koff[kb][s] = row * 64 + ((c ^ (row & 7)) << 3);
    }
  }
  int voff[2][2][2];
#pragma unroll
  for (int kb = 0; kb < 2; ++kb)
#pragma unroll
    for (int db = 0; db < 2; ++db) {
      const int row = db * 32 + l31;
#pragma unroll
      for (int t = 0; t < 2; ++t) {
        const int c = wkv * 8 + kb * 4 + t * 2 + hi;
        voff[kb][db][t] = row * 128 + ((c ^ (row & 15)) << 3);
      }
    }

  __syncthreads();

  float psum[2] = {0.f, 0.f};
  f32x16 oacc[2][2] = {};   // [qsub][db]: D[d][q], d = db*32 + crow(reg,hi)

  for (int it = 0; it < 16; ++it) {
    const int buf = it & 1;
    const unsigned short* kbuf = (const unsigned short*)(smem + buf * 16384);
    const unsigned short* vbuf =
        (const unsigned short*)(smem + 32768 + buf * 16384);
    if (it < 15)
      stage_kv(Kh, Vh, (it + 1) * 128,
               (unsigned short*)(smem + (buf ^ 1) * 16384),
               (unsigned short*)(smem + 32768 + (buf ^ 1) * 16384), tid);

#pragma unroll
    for (int kb = 0; kb < 2; ++kb) {
      bf16x8 kf[4], vf[2][2];
#pragma unroll
      for (int s = 0; s < 4; ++s)
        kf[s] = *(const bf16x8*)(kbuf + koff[kb][s]);
#pragma unroll
      for (int db = 0; db < 2; ++db)
#pragma unroll
        for (int t = 0; t < 2; ++t)
          vf[db][t] = *(const bf16x8*)(vbuf + voff[kb][db][t]);

#pragma unroll
      for (int qs = 0; qs < 2; ++qs) {
        f32x16 sc = {};
#pragma unroll
        for (int s = 0; s < 4; ++s)
          sc = mfma32(kf[s], qf[qs][s], sc);

        float e[16];
#pragma unroll
        for (int r = 0; r < 16; ++r) e[r] = exp2fast(sc[r]);
        {
          float t0 = (e[0] + e[1]) + (e[2] + e[3]);
          float t1 = (e[4] + e[5]) + (e[6] + e[7]);
          float t2 = (e[8] + e[9]) + (e[10] + e[11]);
          float t3 = (e[12] + e[13]) + (e[14] + e[15]);
          psum[qs] += (t0 + t1) + (t2 + t3);
        }
        unsigned p[8];
#pragma unroll
        for (int j = 0; j < 8; ++j) p[j] = cvt_pk_bf16(e[2 * j], e[2 * j + 1]);
        // redistribute into 32x32x16 B-fragment layout (2 swaps per 16-kv)
        pl32_swap(p[0], p[2]); pl32_swap(p[1], p[3]);   // kv [0,16)
        pl32_swap(p[4], p[6]); pl32_swap(p[5], p[7]);   // kv [16,32)
        uint4v u0 = {p[0], p[1], p[2], p[3]};
        uint4v u1 = {p[4], p[5], p[6], p[7]};
        const bf16x8 B0 = __builtin_bit_cast(bf16x8, u0);
        const bf16x8 B1 = __builtin_bit_cast(bf16x8, u1);
#pragma unroll
        for (int db = 0; db < 2; ++db) {
          oacc[qs][db] = mfma32(vf[db][0], B0, oacc[qs][db]);
          oacc[qs][db] = mfma32(vf[db][1], B1, oacc[qs][db]);
        }
      }
    }
    __syncthreads();
  }

  // combine the two hi-halves of each q-row's partial sum
#pragma unroll
  for (int qs = 0; qs < 2; ++qs)
    psum[qs] += __shfl_xor(psum[qs], 32, 64);

  float* red = (float*)smem;               // 128 x 68 floats = 34816 B
  float* psred = (float*)(smem + 34816);   // 128 floats
  if (wkv == 1) {
#pragma unroll
    for (int qs = 0; qs < 2; ++qs) {
      const int qi = wq * 64 + qs * 32 + l31;
      if (hi == 0) psred[qi] = psum[qs];
#pragma unroll
      for (int db = 0; db < 2; ++db)
#pragma unroll
        for (int g = 0; g < 4; ++g) {
          f32x4 ov;
          ov[0] = oacc[qs][db][4 * g + 0];
          ov[1] = oacc[qs][db][4 * g + 1];
          ov[2] = oacc[qs][db][4 * g + 2];
          ov[3] = oacc[qs][db][4 * g + 3];
          *(f32x4*)(red + qi * 68 + db * 32 + g * 8 + hi * 4) = ov;
        }
    }
  }
  __syncthreads();
  if (wkv == 0) {
#pragma unroll
    for (int qs = 0; qs < 2; ++qs) {
      const int qi = wq * 64 + qs * 32 + l31;
      const float inv = 1.0f / (psum[qs] + psred[qi]);
      const size_t row = (size_t)(b * 2048 + q0 + qi);
#pragma unroll
      for (int db = 0; db < 2; ++db)
#pragma unroll
        for (int g = 0; g < 4; ++g) {
          f32x4 o = *(const f32x4*)(red + qi * 68 + db * 32 + g * 8 + hi * 4);
          ushort4 st;
          st.x = f2bf((o[0] + oacc[qs][db][4 * g + 0]) * inv);
          st.y = f2bf((o[1] + oacc[qs][db][4 * g + 1]) * inv);
          st.z = f2bf((o[2] + oacc[qs][db][4 * g + 2]) * inv);
          st.w = f2bf((o[3] + oacc[qs][db][4 * g + 3]) * inv);
          *(ushort4*)(ctx + row * 1024 + colbase + db * 32 + g * 8 + hi * 4) =
              st;
        }
    }
  }
}

// -------- output projection: o128 x s64 tile, BK=64, swizzled LDS --------
__launch_bounds__(256, 4)
__global__ void out_gemm(const unsigned short* __restrict__ A,   // ctx [4096][1024]
                         const unsigned short* __restrict__ Wb,  // Wo   [1024][1024]
                         const float* __restrict__ bo,
                         float* __restrict__ out) {
  __shared__ unsigned short As[128 * 64];   // Wo rows (o)   16 KB
  __shared__ unsigned short Bs[64 * 64];    // ctx rows (s)   8 KB
  const int s0 = blockIdx.x * 64;
  const int o0 = blockIdx.y * 128;

  const int tid = threadIdx.x;
  const int lane = tid & 63;
  const int wid = tid >> 6;
  const int wm = (wid >> 1) * 64;   // o
  const int wn = (wid & 1) * 32;    // s
  const int lm = lane & 15;
  const int quad = lane >> 4;

  f32x4 acc[4][2] = {};

  for (int kk = 0; kk < 1024; kk += 64) {
#pragma unroll
    for (int t = 0; t < 4; ++t) {
      int i = t * 256 + tid;
      int row = i >> 3, tp = i & 7;
      int seg = tp ^ (row & 7);
      gload16(Wb + (size_t)(o0 + row) * 1024 + kk + seg * 8, As + (size_t)i * 8);
    }
#pragma unroll
    for (int t = 0; t < 2; ++t) {
      int i = t * 256 + tid;
      int row = i >> 3, tp = i & 7;
      int seg = tp ^ (row & 7);
      gload16(A + (size_t)(s0 + row) * 1024 + kk + seg * 8, Bs + (size_t)i * 8);
    }
    __syncthreads();
#pragma unroll
    for (int h = 0; h < 2; ++h) {
      bf16x8 af[4], bff[2];
#pragma unroll
      for (int mt = 0; mt < 4; ++mt) {
        int r = wm + mt * 16 + lm;
        af[mt] = *(const bf16x8*)(As + r * 64 + (((h * 4 + quad) ^ (r & 7)) * 8));
      }
#pragma unroll
      for (int nt = 0; nt < 2; ++nt) {
        int r = wn + nt * 16 + lm;
        bff[nt] = *(const bf16x8*)(Bs + r * 64 + (((h * 4 + quad) ^ (r & 7)) * 8));
      }
#pragma unroll
      for (int mt = 0; mt < 4; ++mt)
#pragma unroll
        for (int nt = 0; nt < 2; ++nt)
          acc[mt][nt] = __builtin_amdgcn_mfma_f32_16x16x32_bf16(
              af[mt], bff[nt], acc[mt][nt], 0, 0, 0);
    }
    __syncthreads();
  }

#pragma unroll
  for (int mt = 0; mt < 4; ++mt) {
    const int o = o0 + wm + mt * 16 + quad * 4;
    const float4 bb = *(const float4*)(bo + o);
#pragma unroll
    for (int nt = 0; nt < 2; ++nt) {
      const int s = s0 + wn + nt * 16 + lm;
      float4 v;
      v.x = acc[mt][nt][0] + bb.x;
      v.y = acc[mt][nt][1] + bb.y;
      v.z = acc[mt][nt][2] + bb.z;
      v.w = acc[mt][nt][3] + bb.w;
      *(float4*)(out + (size_t)s * 1024 + o) = v;
    }
  }
}

extern "C" void kernel_launch(void* const* d_in, const int* in_sizes, int n_in,
                              void* d_out, int out_size, void* d_ws, size_t ws_size,
                              hipStream_t stream) {
  const float* x  = (const float*)d_in[0];
  const float* Wq = (const float*)d_in[1];
  const float* bq = (const float*)d_in[2];
  const float* Wk = (const float*)d_in[3];
  const float* bk = (const float*)d_in[4];
  const float* Wv = (const float*)d_in[5];
  const float* bv = (const float*)d_in[6];
  const float* Wo = (const float*)d_in[7];
  const float* bo = (const float*)d_in[8];
  float* out = (float*)d_out;

  char* ws = (char*)d_ws;
  unsigned short* xb  = (unsigned short*)(ws + 0);          //  8 MB
  unsigned short* wqb = (unsigned short*)(ws + 8388608);    //  2 MB
  unsigned short* wkb = (unsigned short*)(ws + 10485760);   //  2 MB
  unsigned short* wvb = (unsigned short*)(ws + 12582912);   //  2 MB
  unsigned short* wob = (unsigned short*)(ws + 14680064);   //  2 MB
  unsigned short* Qb  = (unsigned short*)(ws + 16777216);   //  8 MB [32][2048][64]
  unsigned short* Kb  = (unsigned short*)(ws + 25165824);   //  8 MB [32][2048][64]
  unsigned short* VTb = (unsigned short*)(ws + 33554432);   //  8 MB [32][64][2048]
  unsigned short* ctxb= (unsigned short*)(ws + 41943040);   //  8 MB [4096][1024]
  if (ws_size < 50331648) return;

  cvt_all<<<8192, 256, 0, stream>>>(x, Wq, Wk, Wv, Wo, (ushort4*)ws);
  qkv_gemm<<<dim3(32, 24), 256, 0, stream>>>(xb, wqb, wkb, wvb, bq, bk, bv,
                                             Qb, Kb, VTb);
  attn_kernel<<<dim3(512), 256, 0, stream>>>(Qb, Kb, VTb, ctxb);
  out_gemm<<<dim3(64, 8), 256, 0, stream>>>(ctxb, wob, bo, out);
}